// Round 3
// baseline (5037.172 us; speedup 1.0000x reference)
//
#include <hip/hip_runtime.h>
#include <hip/hip_bf16.h>
#include <math.h>

// Problem constants
#define D_MODEL 2048
#define D_FF    8192
#define MTOK    8192        // 4*2048 tokens
#define GSIZE   64
#define QBF     127.0f
#define EPSQ    1e-5f
#define W_NUMEL (D_FF * D_MODEL)        // 16,777,216 for all three weights
#define W_INV_NUMEL (1.0f / 16777216.0f)

typedef unsigned short u16;
typedef __attribute__((ext_vector_type(8))) short short8;   // 8 bf16 (A/B frag)
typedef __attribute__((ext_vector_type(4))) float f32x4;    // C/D frag
typedef __attribute__((ext_vector_type(4))) unsigned int u32x4;
typedef __attribute__((ext_vector_type(4))) unsigned short u16x4;

// ---------------- mean(|w|) reduction: sum into out[0] -----------------
__global__ void absmean_kernel(const float* __restrict__ w, float* __restrict__ out, int n4) {
    const f32x4* w4 = (const f32x4*)w;
    float s = 0.f;
    for (int i = blockIdx.x * blockDim.x + threadIdx.x; i < n4; i += gridDim.x * blockDim.x) {
        f32x4 v = w4[i];
        s += fabsf(v[0]) + fabsf(v[1]) + fabsf(v[2]) + fabsf(v[3]);
    }
    #pragma unroll
    for (int off = 32; off > 0; off >>= 1) s += __shfl_xor(s, off);
    if ((threadIdx.x & 63) == 0) atomicAdd(out, s);
}

// ---------------- per-group activation quant ---------------------------
// X: [M, K=gpr*64] fp32 -> Q int-valued-bf16 (exact), SdivT[gi*M + row] = s/127
__global__ void quant_kernel(const float* __restrict__ X, u16* __restrict__ Q,
                             float* __restrict__ SdivT, int M, int gpr) {
    const int lane = threadIdx.x & 63;
    const int K = gpr * GSIZE;
    int wid = (blockIdx.x * blockDim.x + threadIdx.x) >> 6;
    const int nwaves = (gridDim.x * blockDim.x) >> 6;
    const int total = M * gpr;
    for (int G = wid; G < total; G += nwaves) {
        int row = G / gpr;
        int gi  = G - row * gpr;
        size_t base = (size_t)row * K + gi * GSIZE;
        float v = X[base + lane];
        float a = fabsf(v);
        #pragma unroll
        for (int off = 32; off > 0; off >>= 1) a = fmaxf(a, __shfl_xor(a, off));
        float s = fmaxf(a, EPSQ);
        float rinv = QBF / s;                         // matches ref: QB / s (division first)
        float q = rintf(fminf(fmaxf(v * rinv, -QBF), QBF));  // clip then round-half-even
        union { float f; unsigned u; } cv; cv.f = q;
        Q[base + lane] = (u16)(cv.u >> 16);           // |q|<=127 integer -> exact bf16
        if (lane == 0) SdivT[(size_t)gi * M + row] = s / QBF;
    }
}

// ---------------- bit-GEMM: C[M,N] = sum_g sdiv[m,g] * (sum_{k in g} q[m,k]*sign(W[n,k])) * wscale
// A: qx int-bf16 [Mtot,K]; W: fp32 [N,K] (torch Linear layout); SdivT: [K/64, Mtot]
// EPI 0: Y[m,n] = acc*wsc          (y1 / final out)
// EPI 1: Y[m,n] = silu(Y1[m,n]) * acc*wsc   (fused SwiGLU gate)
template<int EPI>
__global__ __launch_bounds__(256, 2)
void gemm_bit(const u16* __restrict__ Aq, const float* __restrict__ SdivT,
              const float* __restrict__ W, const float* __restrict__ wsum,
              float* __restrict__ Y, const float* __restrict__ Y1,
              int N, int K, int Mtot) {
    __shared__ __align__(16) u16  lA[128 * 64];
    __shared__ __align__(16) u16  lB[128 * 64];
    __shared__ __align__(16) float lS[128];

    const int tid  = threadIdx.x;
    const int lane = tid & 63;
    const int wid  = tid >> 6;
    const int quad = lane >> 4;
    const int l16  = lane & 15;
    const int wm = (wid & 1) * 64;
    const int wn = (wid >> 1) * 64;
    const int m0 = blockIdx.y * 128;
    const int n0 = blockIdx.x * 128;

    f32x4 acc[4][4];
    #pragma unroll
    for (int i = 0; i < 4; ++i)
        #pragma unroll
        for (int j = 0; j < 4; ++j) acc[i][j] = (f32x4){0.f, 0.f, 0.f, 0.f};

    const f32x4 czero = {0.f, 0.f, 0.f, 0.f};
    const int G = K >> 6;

    for (int g = 0; g < G; ++g) {
        // ---- stage A tile: 128 rows x 64 bf16 (16B per lane-iter) ----
        #pragma unroll
        for (int i = 0; i < 4; ++i) {
            int idx = tid + i * 256;          // 1024 oct-units (8 bf16 each)
            int row = idx >> 3, oct = idx & 7;
            u32x4 v = *(const u32x4*)(Aq + (size_t)(m0 + row) * K + g * 64 + oct * 8);
            *(u32x4*)(lA + row * 64 + oct * 8) = v;
        }
        // ---- stage B tile: sign(W) -> ±1 bf16, 128 rows x 64 ----
        #pragma unroll
        for (int i = 0; i < 8; ++i) {
            int idx = tid + i * 256;          // 2048 quad-units (4 fp32 each)
            int row = idx >> 4, q4 = idx & 15;
            f32x4 w = *(const f32x4*)(W + (size_t)(n0 + row) * K + g * 64 + q4 * 4);
            u16x4 sg;
            #pragma unroll
            for (int c = 0; c < 4; ++c) {
                float wv = w[c];
                sg[c] = (wv == 0.f) ? (u16)0
                        : (u16)(0x3F80u | ((__float_as_uint(wv) >> 16) & 0x8000u));
            }
            *(u16x4*)(lB + row * 64 + q4 * 4) = sg;
        }
        // ---- stage group scales for the 128 A-rows ----
        if (tid < 128) lS[tid] = SdivT[(size_t)g * Mtot + m0 + tid];
        __syncthreads();

        // ---- fragments: A[m=lane&15][k=quad*8+j], B[k=quad*8+j][n=lane&15] ----
        short8 a[4][2];
        #pragma unroll
        for (int mi = 0; mi < 4; ++mi)
            #pragma unroll
            for (int ks = 0; ks < 2; ++ks)
                a[mi][ks] = *(const short8*)(lA + (wm + mi * 16 + l16) * 64 + ks * 32 + quad * 8);
        f32x4 sf[4];
        #pragma unroll
        for (int mi = 0; mi < 4; ++mi)
            sf[mi] = *(const f32x4*)(lS + wm + mi * 16 + quad * 4);

        #pragma unroll
        for (int ni = 0; ni < 4; ++ni) {
            const u16* bp = lB + (wn + ni * 16 + l16) * 64 + quad * 8;
            short8 b0 = *(const short8*)(bp);
            short8 b1 = *(const short8*)(bp + 32);
            #pragma unroll
            for (int mi = 0; mi < 4; ++mi) {
                f32x4 gacc = __builtin_amdgcn_mfma_f32_16x16x32_bf16(a[mi][0], b0, czero, 0, 0, 0);
                gacc = __builtin_amdgcn_mfma_f32_16x16x32_bf16(a[mi][1], b1, gacc, 0, 0, 0);
                acc[mi][ni] += gacc * sf[mi];   // exact int group-dot -> fp32 rescale
            }
        }
        __syncthreads();
    }

    const float wsc = wsum[0] * W_INV_NUMEL;   // mean|w|
    #pragma unroll
    for (int mi = 0; mi < 4; ++mi) {
        #pragma unroll
        for (int ni = 0; ni < 4; ++ni) {
            int col = n0 + wn + ni * 16 + l16;
            #pragma unroll
            for (int r = 0; r < 4; ++r) {
                int row = m0 + wm + mi * 16 + quad * 4 + r;   // C/D: col=lane&15, row=quad*4+reg
                size_t o = (size_t)row * N + col;
                float y = acc[mi][ni][r] * wsc;
                if (EPI == 1) {
                    float y1 = Y1[o];
                    float h = (y1 / (1.f + expf(-y1))) * y;   // silu(y1) * y2
                    Y[o] = h;
                } else {
                    Y[o] = y;
                }
            }
        }
    }
}

extern "C" void kernel_launch(void* const* d_in, const int* in_sizes, int n_in,
                              void* d_out, int out_size, void* d_ws, size_t ws_size,
                              hipStream_t stream) {
    const float* x  = (const float*)d_in[0];
    const float* w1 = (const float*)d_in[1];
    const float* w2 = (const float*)d_in[2];
    const float* w3 = (const float*)d_in[3];
    float* out = (float*)d_out;

    // ---- choose chunk size Mc (tokens per pipeline pass) from ws_size ----
    // per-token scratch: qx 2048*2 + sxT 32*4 + y 8192*4 + qh 8192*2 + shT 128*4
    const size_t perTok = (size_t)D_MODEL * 2 + 32 * 4 + (size_t)D_FF * 4
                        + (size_t)D_FF * 2 + 128 * 4;        // 53,888 B
    int Mc = 512;
    for (int cand = MTOK; cand >= 1024; cand >>= 1) {
        if (256 + perTok * (size_t)cand <= ws_size) { Mc = cand; break; }
    }
    const int nChunks = MTOK / Mc;

    // workspace layout (per chunk, reused across chunks)
    char* ws = (char*)d_ws;
    float* wsum = (float*)ws;                                   // 3 floats (256 B slot)
    char* p = ws + 256;
    u16*   qx   = (u16*)p;        p += (size_t)Mc * D_MODEL * 2;
    float* sxT  = (float*)p;      p += (size_t)Mc * 32 * 4;     // [32][Mc]
    float* y    = (float*)p;      p += (size_t)Mc * D_FF * 4;   // fp32 [Mc][8192]
    u16*   qh   = (u16*)p;        p += (size_t)Mc * D_FF * 2;
    float* shT  = (float*)p;                                    // [128][Mc]

    (void)hipMemsetAsync(wsum, 0, 64, stream);
    absmean_kernel<<<512, 256, 0, stream>>>(w1, wsum + 0, W_NUMEL / 4);
    absmean_kernel<<<512, 256, 0, stream>>>(w2, wsum + 1, W_NUMEL / 4);
    absmean_kernel<<<512, 256, 0, stream>>>(w3, wsum + 2, W_NUMEL / 4);

    for (int c = 0; c < nChunks; ++c) {
        const float* xc = x + (size_t)c * Mc * D_MODEL;
        float* outc     = out + (size_t)c * Mc * D_MODEL;

        quant_kernel<<<1024, 256, 0, stream>>>(xc, qx, sxT, Mc, D_MODEL / GSIZE);

        dim3 g1(D_FF / 128, Mc / 128);
        gemm_bit<0><<<g1, 256, 0, stream>>>(qx, sxT, w1, wsum + 0, y, nullptr, D_FF, D_MODEL, Mc);
        gemm_bit<1><<<g1, 256, 0, stream>>>(qx, sxT, w2, wsum + 1, y, y, D_FF, D_MODEL, Mc);

        quant_kernel<<<2048, 256, 0, stream>>>(y, qh, shT, Mc, D_FF / GSIZE);

        dim3 g2(D_MODEL / 128, Mc / 128);
        gemm_bit<0><<<g2, 256, 0, stream>>>(qh, shT, w3, wsum + 2, outc, nullptr, D_MODEL, D_FF, Mc);
    }
}

// Round 4
// 1934.826 us; speedup vs baseline: 2.6034x; 2.6034x over previous
//
#include <hip/hip_runtime.h>
#include <hip/hip_bf16.h>
#include <math.h>

// Problem constants
#define D_MODEL 2048
#define D_FF    8192
#define MTOK    8192        // 4*2048 tokens
#define GSIZE   64
#define QBF     127.0f
#define EPSQ    1e-5f
#define W_NUMEL (D_FF * D_MODEL)        // 16,777,216 for all three weights
#define W_INV_NUMEL (1.0f / 16777216.0f)

typedef unsigned short u16;
typedef __attribute__((ext_vector_type(8))) short short8;   // 8 bf16 (A/B frag)
typedef __attribute__((ext_vector_type(4))) float f32x4;    // C/D frag
typedef __attribute__((ext_vector_type(4))) unsigned int u32x4;
typedef __attribute__((ext_vector_type(4))) unsigned short u16x4;

// Async global->LDS, 16B per lane. LDS image must be linear in lane order.
__device__ __forceinline__ void gload_lds16(const void* g, void* l) {
    __builtin_amdgcn_global_load_lds(
        (const __attribute__((address_space(1))) unsigned int*)g,
        (__attribute__((address_space(3))) unsigned int*)l, 16, 0, 0);
}

// Tile-swizzled element offset (u16 units) for logical (tileIdx, r, k):
//   off = tileIdx*8192 + r*64 + ((c ^ (r&7))*8) + j,  c=(k&63)>>3, j=k&7
// This makes a 128x64 bf16 tile a contiguous 16 KB block whose ds_read_b128
// fragment loads are bank-conflict-free (XOR swizzle breaks the 128B-row
// stride that put all 16 lanes of a quad on the same 4 banks in round 3).

// ---------------- mean(|w|) reduction: sum into out[0] -----------------
__global__ void absmean_kernel(const float* __restrict__ w, float* __restrict__ out, int n4) {
    const f32x4* w4 = (const f32x4*)w;
    float s = 0.f;
    for (int i = blockIdx.x * blockDim.x + threadIdx.x; i < n4; i += gridDim.x * blockDim.x) {
        f32x4 v = w4[i];
        s += fabsf(v[0]) + fabsf(v[1]) + fabsf(v[2]) + fabsf(v[3]);
    }
    #pragma unroll
    for (int off = 32; off > 0; off >>= 1) s += __shfl_xor(s, off);
    if ((threadIdx.x & 63) == 0) atomicAdd(out, s);
}

// ---------------- weight pack: fp32 [N,K] -> +-1 bf16, swizzled tiles ----
__global__ void wpack_kernel(const float* __restrict__ W, u16* __restrict__ Wb,
                             int N, int K) {
    const int Gk = K >> 6;
    const int cpr = K >> 3;                 // 8-elem chunks per row
    int idx = blockIdx.x * blockDim.x + threadIdx.x;
    if (idx >= N * cpr) return;
    int row = idx / cpr;
    int ck  = idx - row * cpr;
    int k0  = ck << 3;
    const float* src = W + (size_t)row * K + k0;
    f32x4 w0 = *(const f32x4*)src;
    f32x4 w1 = *(const f32x4*)(src + 4);
    unsigned hw[8];
    #pragma unroll
    for (int i = 0; i < 8; ++i) {
        float wv = (i < 4) ? w0[i] : w1[i - 4];
        hw[i] = (wv == 0.f) ? 0u : (0x3F80u | ((__float_as_uint(wv) >> 16) & 0x8000u));
    }
    u32x4 o;
    #pragma unroll
    for (int p = 0; p < 4; ++p) o[p] = hw[2 * p] | (hw[2 * p + 1] << 16);
    int nt = row >> 7, r = row & 127;
    int g = k0 >> 6, c8 = (k0 & 63) >> 3;
    size_t dst = ((size_t)(nt * Gk + g) << 13) + (size_t)r * 64 + (size_t)((c8 ^ (r & 7)) << 3);
    *(u32x4*)(Wb + dst) = o;
}

// ---------------- per-group activation quant (swizzled tile output) ------
// X: [M, K=Gk*64] fp32 -> Q int-valued-bf16 swizzled tiles, SdivT[g][M]=s/127
// One wave covers 256 consecutive k of one row (= 4 quant groups of 64).
__global__ void quant_kernel(const float* __restrict__ X, u16* __restrict__ Q,
                             float* __restrict__ SdivT, int M, int Gk) {
    const int K = Gk << 6;
    const int lane = threadIdx.x & 63;
    const int segs = K >> 8;
    int widx = (blockIdx.x * blockDim.x + threadIdx.x) >> 6;
    if (widx >= M * segs) return;
    int row = widx / segs;
    int seg = widx - row * segs;
    int k0 = (seg << 8) + lane * 4;
    f32x4 v = *(const f32x4*)(X + (size_t)row * K + k0);
    float a = fmaxf(fmaxf(fabsf(v[0]), fabsf(v[1])), fmaxf(fabsf(v[2]), fabsf(v[3])));
    a = fmaxf(a, __shfl_xor(a, 1));
    a = fmaxf(a, __shfl_xor(a, 2));
    a = fmaxf(a, __shfl_xor(a, 4));
    a = fmaxf(a, __shfl_xor(a, 8));          // max over the 16-lane (64-elem) group
    float s = fmaxf(a, EPSQ);
    float rinv = QBF / s;                    // matches ref: QB / s
    u16x4 qo;
    #pragma unroll
    for (int c = 0; c < 4; ++c) {
        float q = rintf(fminf(fmaxf(v[c] * rinv, -QBF), QBF));   // clip then rne
        qo[c] = (u16)(__float_as_uint(q) >> 16);                 // exact int bf16
    }
    int mt = row >> 7, r = row & 127;
    int gi = k0 >> 6;                        // group index along K
    int c8 = (k0 & 63) >> 3;
    int j0 = k0 & 7;                         // 0 or 4
    size_t dst = ((size_t)(mt * Gk + gi) << 13) + (size_t)r * 64
               + (size_t)((c8 ^ (r & 7)) << 3) + j0;
    *(u16x4*)(Q + dst) = qo;
    if ((lane & 15) == 0) SdivT[(size_t)gi * M + row] = s / QBF;
}

// ---------------- bit-GEMM (m97-style: global_load_lds + swizzled LDS) ---
// A: swizzled qx tiles [Mtot/128][G][8192]; Wb: swizzled +-1 bf16 tiles
// SdivT: [G][Mtot]. EPI 0: Y=acc*wsc ; EPI 1: Y=silu(Y1)*acc*wsc
template<int EPI>
__global__ __launch_bounds__(256, 3)
void gemm_bit(const u16* __restrict__ Aq, const float* __restrict__ SdivT,
              const u16* __restrict__ Wb, const float* __restrict__ wsum,
              float* __restrict__ Y, const float* __restrict__ Y1,
              int N, int G, int Mtot) {
    __shared__ __align__(16) u16  lA[8192];
    __shared__ __align__(16) u16  lB[8192];
    __shared__ __align__(16) float lS[128];

    const int tid  = threadIdx.x;
    const int lane = tid & 63;
    const int wid  = tid >> 6;
    const int quad = lane >> 4;
    const int l16  = lane & 15;
    const int wm = (wid & 1) * 64;
    const int wn = (wid >> 1) * 64;
    const int m0 = blockIdx.y * 128;
    const int n0 = blockIdx.x * 128;

    const char* gA = (const char*)(Aq + ((size_t)blockIdx.y * G << 13));
    const char* gB = (const char*)(Wb + ((size_t)blockIdx.x * G << 13));
    char* dA = (char*)lA + tid * 16;
    char* dB = (char*)lB + tid * 16;

    f32x4 acc[4][4];
    #pragma unroll
    for (int i = 0; i < 4; ++i)
        #pragma unroll
        for (int j = 0; j < 4; ++j) acc[i][j] = (f32x4){0.f, 0.f, 0.f, 0.f};
    const f32x4 czero = {0.f, 0.f, 0.f, 0.f};

    for (int g = 0; g < G; ++g) {
        __syncthreads();                       // prior iter done reading LDS
        const char* sA = gA + ((size_t)g << 14);   // 16 KB per tile
        const char* sB = gB + ((size_t)g << 14);
        #pragma unroll
        for (int i = 0; i < 4; ++i) gload_lds16(sA + tid * 16 + i * 4096, dA + i * 4096);
        #pragma unroll
        for (int i = 0; i < 4; ++i) gload_lds16(sB + tid * 16 + i * 4096, dB + i * 4096);
        if (tid < 128) lS[tid] = SdivT[(size_t)g * Mtot + m0 + tid];
        __syncthreads();                       // drains vmcnt -> tiles visible

        short8 a[4][2];
        #pragma unroll
        for (int mi = 0; mi < 4; ++mi)
            #pragma unroll
            for (int ks = 0; ks < 2; ++ks) {
                int r = wm + mi * 16 + l16;
                int c = ks * 4 + quad;
                a[mi][ks] = *(const short8*)(lA + r * 64 + ((c ^ (r & 7)) << 3));
            }
        f32x4 sf[4];
        #pragma unroll
        for (int mi = 0; mi < 4; ++mi)
            sf[mi] = *(const f32x4*)(lS + wm + mi * 16 + quad * 4);

        #pragma unroll
        for (int ni = 0; ni < 4; ++ni) {
            int rb = wn + ni * 16 + l16;
            short8 b0 = *(const short8*)(lB + rb * 64 + ((quad ^ (rb & 7)) << 3));
            short8 b1 = *(const short8*)(lB + rb * 64 + (((4 + quad) ^ (rb & 7)) << 3));
            #pragma unroll
            for (int mi = 0; mi < 4; ++mi) {
                f32x4 t = __builtin_amdgcn_mfma_f32_16x16x32_bf16(a[mi][0], b0, czero, 0, 0, 0);
                t = __builtin_amdgcn_mfma_f32_16x16x32_bf16(a[mi][1], b1, t, 0, 0, 0);
                acc[mi][ni] += t * sf[mi];     // exact int group-dot -> fp32 rescale
            }
        }
    }

    const float wsc = wsum[0] * W_INV_NUMEL;   // mean|w|
    #pragma unroll
    for (int mi = 0; mi < 4; ++mi) {
        #pragma unroll
        for (int ni = 0; ni < 4; ++ni) {
            int col = n0 + wn + ni * 16 + l16;
            #pragma unroll
            for (int r = 0; r < 4; ++r) {
                int row = m0 + wm + mi * 16 + quad * 4 + r;   // C/D: col=lane&15, row=quad*4+reg
                size_t o = (size_t)row * N + col;
                float y = acc[mi][ni][r] * wsc;
                if (EPI == 1) {
                    float y1 = Y1[o];
                    float h = (y1 / (1.f + expf(-y1))) * y;   // silu(y1) * y2
                    Y[o] = h;
                } else {
                    Y[o] = y;
                }
            }
        }
    }
}

extern "C" void kernel_launch(void* const* d_in, const int* in_sizes, int n_in,
                              void* d_out, int out_size, void* d_ws, size_t ws_size,
                              hipStream_t stream) {
    const float* x  = (const float*)d_in[0];
    const float* w1 = (const float*)d_in[1];
    const float* w2 = (const float*)d_in[2];
    const float* w3 = (const float*)d_in[3];
    float* out = (float*)d_out;

    // ---- workspace layout: packed weights (fixed) + chunked activations ----
    char* ws = (char*)d_ws;
    const size_t wbBytes = (size_t)W_NUMEL * 2;        // 32 MB per packed weight
    float* wsum = (float*)ws;
    char* p = ws + 256;
    u16* w1b = (u16*)p;  p += wbBytes;
    u16* w2b = (u16*)p;  p += wbBytes;
    u16* w3b = (u16*)p;  p += wbBytes;
    size_t fixed = (size_t)(p - ws);

    // per-token: qx 4096 + sxT 128 + y 32768 + qh 16384 + shT 512 = 53,888 B
    const size_t perTok = (size_t)D_MODEL * 2 + 32 * 4 + (size_t)D_FF * 4
                        + (size_t)D_FF * 2 + 128 * 4;
    int Mc = 512;
    for (int cand = MTOK; cand >= 1024; cand >>= 1) {
        if (fixed + perTok * (size_t)cand <= ws_size) { Mc = cand; break; }
    }
    const int nChunks = MTOK / Mc;

    u16*   qx  = (u16*)p;         p += (size_t)Mc * D_MODEL * 2;
    float* sxT = (float*)p;       p += (size_t)Mc * 32 * 4;      // [32][Mc]
    float* y   = (float*)p;       p += (size_t)Mc * D_FF * 4;
    u16*   qh  = (u16*)p;         p += (size_t)Mc * D_FF * 2;
    float* shT = (float*)p;                                      // [128][Mc]

    (void)hipMemsetAsync(wsum, 0, 64, stream);
    absmean_kernel<<<512, 256, 0, stream>>>(w1, wsum + 0, W_NUMEL / 4);
    absmean_kernel<<<512, 256, 0, stream>>>(w2, wsum + 1, W_NUMEL / 4);
    absmean_kernel<<<512, 256, 0, stream>>>(w3, wsum + 2, W_NUMEL / 4);

    // pack weights once per launch (N*K/8 threads each)
    wpack_kernel<<<W_NUMEL / 8 / 256, 256, 0, stream>>>(w1, w1b, D_FF, D_MODEL);
    wpack_kernel<<<W_NUMEL / 8 / 256, 256, 0, stream>>>(w2, w2b, D_FF, D_MODEL);
    wpack_kernel<<<W_NUMEL / 8 / 256, 256, 0, stream>>>(w3, w3b, D_MODEL, D_FF);

    for (int c = 0; c < nChunks; ++c) {
        const float* xc = x + (size_t)c * Mc * D_MODEL;
        float* outc     = out + (size_t)c * Mc * D_MODEL;

        quant_kernel<<<Mc * D_MODEL / 1024, 256, 0, stream>>>(xc, qx, sxT, Mc, D_MODEL / GSIZE);

        dim3 g1(D_FF / 128, Mc / 128);
        gemm_bit<0><<<g1, 256, 0, stream>>>(qx, sxT, w1b, wsum + 0, y, nullptr,
                                            D_FF, D_MODEL / GSIZE, Mc);
        gemm_bit<1><<<g1, 256, 0, stream>>>(qx, sxT, w2b, wsum + 1, y, y,
                                            D_FF, D_MODEL / GSIZE, Mc);

        quant_kernel<<<Mc * D_FF / 1024, 256, 0, stream>>>(y, qh, shT, Mc, D_FF / GSIZE);

        dim3 g2(D_MODEL / 128, Mc / 128);
        gemm_bit<0><<<g2, 256, 0, stream>>>(qh, shT, w3b, wsum + 2, outc, nullptr,
                                            D_MODEL, D_FF / GSIZE, Mc);
    }
}